// Round 13
// baseline (159.811 us; speedup 1.0000x reference)
//
#include <hip/hip_runtime.h>

#define BATCH 4
#define SEQ   4096
#define CDIM  1024
#define DDIM  64
#define NROW  (BATCH * SEQ)   // 16384
#define NSPL  8               // attn key-split
#define KS    4               // proj K-split (across blocks)
#define SEG   (NROW * DDIM)   // 1M elements per partial segment

typedef _Float16 f16;
typedef _Float16 f16x8 __attribute__((ext_vector_type(8)));
typedef _Float16 f16x4 __attribute__((ext_vector_type(4)));
typedef __fp16   h16x2 __attribute__((ext_vector_type(2)));  // cvt_pkrtz return type
typedef float    f32x4 __attribute__((ext_vector_type(4)));

#define MFMA32(a, b, c) __builtin_amdgcn_mfma_f32_16x16x32_f16((a), (b), (c), 0, 0, 0)
#define MFMA16(a, b, c) __builtin_amdgcn_mfma_f32_16x16x16f16((a), (b), (c), 0, 0, 0)

// async global->LDS DMA, 16 B per lane; LDS dest = wave-uniform base + lane*16
#define GLDS(g, l)                                                            \
  __builtin_amdgcn_global_load_lds((const __attribute__((address_space(1))) void*)(g), \
                                   (__attribute__((address_space(3))) void*)(l), 16, 0, 0)

// scores = (q·k)*8 (the /scale bug); softmax in exp2 domain => fold 8*log2(e) into q
#define QSCALE 11.5415603f

__device__ inline f16x8 cvt8(f32x4 a, f32x4 b) {
  h16x2 p0 = __builtin_amdgcn_cvt_pkrtz(a[0], a[1]);
  h16x2 p1 = __builtin_amdgcn_cvt_pkrtz(a[2], a[3]);
  h16x2 p2 = __builtin_amdgcn_cvt_pkrtz(b[0], b[1]);
  h16x2 p3 = __builtin_amdgcn_cvt_pkrtz(b[2], b[3]);
  f16x8 r;
  r[0] = p0[0]; r[1] = p0[1]; r[2] = p1[0]; r[3] = p1[1];
  r[4] = p2[0]; r[5] = p2[1]; r[6] = p3[0]; r[7] = p3[1];
  return r;
}

__device__ inline f16x4 cvt4(float a, float b, float c, float d) {
  h16x2 lo = __builtin_amdgcn_cvt_pkrtz(a, b);
  h16x2 hi = __builtin_amdgcn_cvt_pkrtz(c, d);
  f16x4 r;
  r[0] = lo[0]; r[1] = lo[1]; r[2] = hi[0]; r[3] = hi[1];
  return r;
}

// ---------------- W prep: fp32 -> f16, shuffled into per-chunk DMA order ------
__global__ __launch_bounds__(256) void prep_w_kernel(const float* __restrict__ Wq,
                                                     const float* __restrict__ Wk,
                                                     const float* __restrict__ Wv,
                                                     f16* __restrict__ wf2) {
  const int t = blockIdx.x * 256 + threadIdx.x;  // 96 blocks -> 24576 threads
  const int lane = t & 63;
  const int s = t >> 6;                // 0..383
  const int mt = s % 12, ck = s / 12;
  const int mat = mt >> 2, tile = mt & 3;
  const int n = lane & 15, quad = lane >> 4;
  const float* W = (mat == 0) ? Wq : (mat == 1) ? Wk : Wv;
  const float* src = W + (size_t)(tile * 16 + n) * CDIM + ck * 32 + quad * 8;
  const f32x4 a = *(const f32x4*)src;
  const f32x4 b = *(const f32x4*)(src + 4);
  *(f16x8*)(wf2 + (size_t)t * 8) = cvt8(a, b);
}

// ---------------- fused QKV projection: K-split-4 DMA pipeline (r12) ----------
__global__ __launch_bounds__(256, 4) void proj_kernel(const float* __restrict__ x,
                                                      const f16* __restrict__ wf2,
                                                      f16* __restrict__ ppart) {
  __shared__ __attribute__((aligned(16))) char smem[2][20480];  // [x 8K | w 12K]
  const int tid = threadIdx.x, lane = tid & 63, w = tid >> 6;
  const int n = lane & 15, quad = lane >> 4;
  const int rw = w & 1, wc = w >> 1;
  const int rowblk = blockIdx.x >> 2, split = blockIdx.x & 3;
  const int rowbase = rowblk * 64;

  const float* xsrc[2];
#pragma unroll
  for (int j = 0; j < 2; ++j) {
    const int i = 2 * w + j;
    xsrc[j] = x + (size_t)(rowbase + i * 8 + (lane >> 3)) * CDIM + split * 256 + (lane & 7) * 4;
  }
  const f16* wsrc[3];
#pragma unroll
  for (int j = 0; j < 3; ++j) {
    const int mt = 3 * w + j;
    wsrc[j] = wf2 + (size_t)(split * 96 + mt) * 512 + lane * 8;
  }

  f32x4 acc[2][6];
#pragma unroll
  for (int rt = 0; rt < 2; ++rt)
#pragma unroll
    for (int i = 0; i < 6; ++i) acc[rt][i] = (f32x4){0.f, 0.f, 0.f, 0.f};

  auto issue = [&](int ck, int b) {
    char* base = &smem[b][0];
#pragma unroll
    for (int j = 0; j < 2; ++j)
      GLDS(xsrc[j] + ck * 32, base + (2 * w + j) * 1024);
#pragma unroll
    for (int j = 0; j < 3; ++j)
      GLDS(wsrc[j] + (size_t)ck * 6144, base + 8192 + (3 * w + j) * 1024);
  };

  issue(0, 0);
  for (int ck = 0; ck < 8; ++ck) {
    const int b = ck & 1;
    __syncthreads();
    if (ck + 1 < 8) issue(ck + 1, b ^ 1);
    const char* base = &smem[b][0];
    f16x8 a[2];
#pragma unroll
    for (int rt = 0; rt < 2; ++rt) {
      const int i = rw * 4 + rt * 2 + (n >> 3);
      const float* xp = (const float*)(base + i * 1024 + (n & 7) * 128 + quad * 32);
      a[rt] = cvt8(*(const f32x4*)xp, *(const f32x4*)(xp + 4));
    }
#pragma unroll
    for (int i2 = 0; i2 < 6; ++i2) {
      const f16x8 bf = *(const f16x8*)(base + 8192 + (wc * 6 + i2) * 1024 + lane * 16);
      acc[0][i2] = MFMA32(a[0], bf, acc[0][i2]);
      acc[1][i2] = MFMA32(a[1], bf, acc[1][i2]);
    }
  }

#pragma unroll
  for (int i2 = 0; i2 < 6; ++i2) {
    const int mt = wc * 6 + i2;
    const int mat = mt >> 2, tile = mt & 3;
    const int d = tile * 16 + n;
    f16* seg = ppart + ((size_t)mat * KS + split) * SEG;
#pragma unroll
    for (int rt = 0; rt < 2; ++rt) {
      const int r0 = rowbase + rw * 32 + rt * 16 + quad * 4;
      const f32x4 aa = acc[rt][i2];
      if (mat == 0) {
#pragma unroll
        for (int r = 0; r < 4; ++r)
          seg[(size_t)(r0 + r) * DDIM + d] = (f16)aa[r];
      } else if (mat == 1) {
#pragma unroll
        for (int r = 0; r < 4; ++r) {
          const int t = r0 + r;
          const int col = ((((d >> 3) ^ (t & 7)) << 3) | (d & 7));
          seg[(size_t)t * DDIM + col] = (f16)aa[r];
        }
      } else {
        const int bb = r0 >> 12;
        const int tl = r0 & (SEQ - 1);
        const int ck2 = tl >> 6;
        const int bsw = (((tl & 63) >> 2) ^ n) << 2;  // d&15 == n
        *(f16x4*)(seg + ((size_t)(bb * 64 + ck2) * 64 + d) * 64 + bsw) =
            cvt4(aa[0], aa[1], aa[2], aa[3]);
      }
    }
  }
}

// ---------------- proj combine: sum K-splits + bias (+QSCALE for q) -----------
__global__ __launch_bounds__(256) void combine_proj_kernel(const f16* __restrict__ ppart,
                                                           const float* __restrict__ bq,
                                                           const float* __restrict__ bk,
                                                           const float* __restrict__ bv,
                                                           f16* __restrict__ qs,
                                                           f16* __restrict__ ks,
                                                           f16* __restrict__ vc) {
  const int seg = blockIdx.x / 512;
  const int tix = (blockIdx.x - seg * 512) * 256 + threadIdx.x;
  const size_t base = (size_t)tix * 8;
  const f16* pp = ppart + (size_t)seg * KS * SEG + base;

  float s[8];
#pragma unroll
  for (int j = 0; j < 8; ++j) s[j] = 0.f;
#pragma unroll
  for (int sp = 0; sp < KS; ++sp) {
    const f16x8 v = *(const f16x8*)(pp + (size_t)sp * SEG);
#pragma unroll
    for (int j = 0; j < 8; ++j) s[j] += (float)v[j];
  }

  f16x8 o;
  if (seg == 0) {
    const int d0 = (int)(base & 63);
#pragma unroll
    for (int j = 0; j < 8; ++j) o[j] = (f16)((s[j] + bq[d0 + j]) * QSCALE);
    *(f16x8*)(qs + base) = o;
  } else if (seg == 1) {
    const int t = (int)(base >> 6);
    const int d0 = (((int)(base & 63) >> 3) ^ (t & 7)) << 3;
#pragma unroll
    for (int j = 0; j < 8; ++j) o[j] = (f16)(s[j] + bk[d0 + j]);
    *(f16x8*)(ks + base) = o;
  } else {
    const float b = bv[(int)(base >> 6) & 63];
#pragma unroll
    for (int j = 0; j < 8; ++j) o[j] = (f16)(s[j] + b);
    *(f16x8*)(vc + base) = o;
  }
}

// ---------------- flash attention: 64 q-rows/wave (4 groups) ------------------
// S' = K·Q^T (C-layout row=key, col=q), per-lane softmax, P stays in registers.
// K frags loaded once/chunk into registers, reused by 4 q-groups (4x amortize);
// V frags reused by 4 groups in PV loop. K/V staged bytes halve vs round 12.
template <int NSPLIT>
__global__ __launch_bounds__(256, 2) void attn_kernel(const f16* __restrict__ qs,
                                                      const f16* __restrict__ ks,
                                                      const f16* __restrict__ vc,
                                                      float* __restrict__ outp,
                                                      f16* __restrict__ pacc,
                                                      float* __restrict__ pm,
                                                      float* __restrict__ pl) {
  __shared__ __attribute__((aligned(16))) f16 lk[2][4096];  // [buf][key][64 d swz]
  __shared__ __attribute__((aligned(16))) f16 lv[2][4096];  // [buf][d][64 key swz]
  const int tid = threadIdx.x, lane = tid & 63, w = tid >> 6;
  const int n = lane & 15, quad = lane >> 4;
  const int split = blockIdx.x % NSPLIT;
  const int rowblk = blockIdx.x / NSPLIT;   // 0..63
  const int row0 = rowblk * 256 + w * 64;   // wave owns 64 q-rows
  const int bb = row0 >> 12;
  const int kbase = split * (SEQ / NSPLIT);
  const int kc0 = kbase >> 6;
  const int NC = SEQ / NSPLIT / 64;

  const f16* ksb = ks + (size_t)bb * SEQ * DDIM;
  const f16* vcb = vc + (size_t)bb * 64 * 4096;

  auto issue = [&](int c, int buf) {
#pragma unroll
    for (int i = 0; i < 2; ++i) {
      const int id = 2 * w + i;
      GLDS(ksb + (size_t)(kbase + c * 64) * 64 + id * 512 + lane * 8, &lk[buf][id * 512]);
      GLDS(vcb + (size_t)(kc0 + c) * 4096 + id * 512 + lane * 8, &lv[buf][id * 512]);
    }
  };

  // persistent Q B-fragments (16x16x32): B[k=d=quad*8+j][col=q=n]
  f16x8 qf[4][2];
#pragma unroll
  for (int g = 0; g < 4; ++g)
#pragma unroll
    for (int hh = 0; hh < 2; ++hh)
      qf[g][hh] = *(const f16x8*)(qs + (size_t)(row0 + g * 16 + n) * DDIM + hh * 32 + quad * 8);

  // swizzle read offsets (per-lane constants)
  const int kswz = (quad ^ (n & 7)) << 3;          // klo block; khi = kswz ^ 32
  int vswz[4];
#pragma unroll
  for (int st = 0; st < 4; ++st) vswz[st] = ((((st << 2) | quad) ^ n) << 2);

  f32x4 acc[4][4];
  float m[4], ll[4];
#pragma unroll
  for (int g = 0; g < 4; ++g) {
    m[g] = -1e30f;
    ll[g] = 0.f;
#pragma unroll
    for (int t = 0; t < 4; ++t) acc[g][t] = (f32x4){0.f, 0.f, 0.f, 0.f};
  }

  issue(0, 0);
  for (int c = 0; c < NC; ++c) {
    const int b = c & 1;
    __syncthreads();                      // drains chunk c's DMA; guards buffers
    if (c + 1 < NC) issue(c + 1, b ^ 1);  // in flight across entire compute phase

    // K fragments once per chunk, reused by all 4 q-groups
    f16x8 kf[4][2];
#pragma unroll
    for (int st = 0; st < 4; ++st) {
      const f16* lkr = &lk[b][(st * 16 + n) * 64];
      kf[st][0] = *(const f16x8*)(lkr + kswz);
      kf[st][1] = *(const f16x8*)(lkr + (kswz ^ 32));
    }

    f16x4 pq[4][4];
#pragma unroll
    for (int g = 0; g < 4; ++g) {
      // S' = K·Q^T for this group
      f32x4 s[4];
#pragma unroll
      for (int st = 0; st < 4; ++st) {
        f32x4 z = (f32x4){0.f, 0.f, 0.f, 0.f};
        z = MFMA32(kf[st][0], qf[g][0], z);
        s[st] = MFMA32(kf[st][1], qf[g][1], z);
      }
      // per-lane online softmax
      f32x4 mx;
#pragma unroll
      for (int r = 0; r < 4; ++r)
        mx[r] = fmaxf(fmaxf(s[0][r], s[1][r]), fmaxf(s[2][r], s[3][r]));
      float mloc = fmaxf(fmaxf(mx[0], mx[1]), fmaxf(mx[2], mx[3]));
      mloc = fmaxf(mloc, __shfl_xor(mloc, 16));
      mloc = fmaxf(mloc, __shfl_xor(mloc, 32));
      const float mnew = fmaxf(m[g], mloc);
      const float alpha = __builtin_amdgcn_exp2f(m[g] - mnew);
      m[g] = mnew;
      float psum = 0.f;
#pragma unroll
      for (int st = 0; st < 4; ++st) {
        f32x4 p;
#pragma unroll
        for (int r = 0; r < 4; ++r) p[r] = __builtin_amdgcn_exp2f(s[st][r] - mnew);
        psum += (p[0] + p[1]) + (p[2] + p[3]);
        pq[g][st] = cvt4(p[0], p[1], p[2], p[3]);
      }
      ll[g] = ll[g] * alpha + psum;
#pragma unroll
      for (int t = 0; t < 4; ++t) acc[g][t] *= alpha;
    }

    // O^T += V^T·P^T : V frag loaded once, used by 4 groups
#pragma unroll
    for (int dt = 0; dt < 4; ++dt) {
      const f16* lvr = &lv[b][(dt * 16 + n) * 64];
#pragma unroll
      for (int st = 0; st < 4; ++st) {
        const f16x4 va = *(const f16x4*)(lvr + vswz[st]);
#pragma unroll
        for (int g = 0; g < 4; ++g)
          acc[g][dt] = MFMA16(va, pq[g][st], acc[g][dt]);
      }
    }
  }

  float lred[4];
#pragma unroll
  for (int g = 0; g < 4; ++g) {
    float l = ll[g];
    l += __shfl_xor(l, 16);
    l += __shfl_xor(l, 32);
    lred[g] = l;
  }

  if (NSPLIT == 1) {
#pragma unroll
    for (int g = 0; g < 4; ++g) {
      const float inv = 1.0f / lred[g];
      const int q = row0 + g * 16 + n;
#pragma unroll
      for (int t = 0; t < 4; ++t) {
        f32x4 o = acc[g][t];
#pragma unroll
        for (int r = 0; r < 4; ++r) o[r] *= inv;
        *(f32x4*)(outp + (size_t)q * DDIM + t * 16 + quad * 4) = o;
      }
    }
  } else {
#pragma unroll
    for (int g = 0; g < 4; ++g) {
      const int q = row0 + g * 16 + n;
#pragma unroll
      for (int t = 0; t < 4; ++t)
        *(f16x4*)(pacc + ((size_t)split * NROW + q) * DDIM + t * 16 + quad * 4) =
            cvt4(acc[g][t][0], acc[g][t][1], acc[g][t][2], acc[g][t][3]);
      if (quad == 0) {
        pm[split * NROW + q] = m[g];
        pl[split * NROW + q] = lred[g];
      }
    }
  }
}

// ---------------- attn split-K combine (f16 partials) ----------------
template <int NSPLIT>
__global__ __launch_bounds__(256) void combine_kernel(const f16* __restrict__ pacc,
                                                      const float* __restrict__ pm,
                                                      const float* __restrict__ pl,
                                                      float* __restrict__ out) {
  const int idx = blockIdx.x * 256 + threadIdx.x;  // NROW*16 units
  const int row = idx >> 4;
  const int c = (idx & 15) * 4;
  float mm = pm[row];
#pragma unroll
  for (int s = 1; s < NSPLIT; ++s) mm = fmaxf(mm, pm[s * NROW + row]);
  float L = 0.f;
  f32x4 o = (f32x4){0.f, 0.f, 0.f, 0.f};
#pragma unroll
  for (int s = 0; s < NSPLIT; ++s) {
    const float e = __builtin_amdgcn_exp2f(pm[s * NROW + row] - mm);
    L += pl[s * NROW + row] * e;
    const f16x4 a = *(const f16x4*)(pacc + ((size_t)s * NROW + row) * DDIM + c);
#pragma unroll
    for (int j = 0; j < 4; ++j) o[j] += (float)a[j] * e;
  }
  const float inv = 1.0f / L;
#pragma unroll
  for (int j = 0; j < 4; ++j) o[j] *= inv;
  *(f32x4*)(out + (size_t)row * DDIM + c) = o;
}

extern "C" void kernel_launch(void* const* d_in, const int* in_sizes, int n_in,
                              void* d_out, int out_size, void* d_ws, size_t ws_size,
                              hipStream_t stream) {
  const float* x  = (const float*)d_in[0];
  const float* Wq = (const float*)d_in[1];
  const float* bq = (const float*)d_in[2];
  const float* Wk = (const float*)d_in[3];
  const float* bk = (const float*)d_in[4];
  const float* Wv = (const float*)d_in[5];
  const float* bv = (const float*)d_in[6];
  float* out = (float*)d_out;

  f16* wf2 = (f16*)d_ws;                      // 3*64*1024 f16, chunk-slot layout
  f16* qs = wf2 + 3 * 65536;
  f16* ks = qs + (size_t)SEG;                 // block-swizzled
  f16* vc = ks + (size_t)SEG;                 // chunk-major tiles, swizzled
  f16* ppart = vc + (size_t)SEG;              // [3][KS][SEG] f16 proj partials
  f16* pacc = ppart + (size_t)3 * KS * SEG;   // [NSPL][NROW][64] f16 attn partials
  float* pm = (float*)(pacc + (size_t)NSPL * SEG);
  float* pl = pm + (size_t)NSPL * NROW;
  const size_t need = (size_t)((char*)(pl + (size_t)NSPL * NROW) - (char*)d_ws);

  prep_w_kernel<<<dim3(96), dim3(256), 0, stream>>>(Wq, Wk, Wv, wf2);
  proj_kernel<<<dim3(256 * KS), dim3(256), 0, stream>>>(x, wf2, ppart);
  combine_proj_kernel<<<dim3(1536), dim3(256), 0, stream>>>(ppart, bq, bk, bv, qs, ks, vc);

  if (ws_size >= need) {
    attn_kernel<NSPL><<<dim3(64 * NSPL), dim3(256), 0, stream>>>(qs, ks, vc, nullptr, pacc, pm, pl);
    combine_kernel<NSPL><<<dim3(NROW * 16 / 256), dim3(256), 0, stream>>>(pacc, pm, pl, out);
  } else {
    attn_kernel<1><<<dim3(64), dim3(256), 0, stream>>>(qs, ks, vc, out, nullptr, nullptr, nullptr);
  }
}